// Round 3
// baseline (358.452 us; speedup 1.0000x reference)
//
#include <hip/hip_runtime.h>
#include <cstddef>
#include <cstdint>

#define NN 20000
#define NE 640000
#define HD 64
#define NC 4
#define CHUNK 160000   // NE / NC

// ---------------- CSR build ----------------
__global__ void zero_kernel(int* __restrict__ p, int n) {
    int i = blockIdx.x * blockDim.x + threadIdx.x;
    if (i < n) p[i] = 0;
}

// chunked histogram: cnt4[c][v], c = edge_index / CHUNK  (contention depth /4)
__global__ void hist_kernel(const int* __restrict__ dst, int* __restrict__ cnt4) {
    int i = blockIdx.x * blockDim.x + threadIdx.x;
    if (i < NE) atomicAdd(&cnt4[(i / CHUNK) * NN + dst[i]], 1);
}

__global__ __launch_bounds__(1024) void scan_kernel(const int* __restrict__ cnt4,
                                                    int* __restrict__ row_ptr,
                                                    int* __restrict__ cursor4) {
    __shared__ int sums[1024];
    int tid = threadIdx.x;
    const int chunk = 20;                 // 1024*20 >= 20000
    int lo = tid * chunk;
    int hi = min(lo + chunk, NN);
    int s = 0;
    for (int i = lo; i < hi; ++i)
        s += cnt4[i] + cnt4[NN + i] + cnt4[2 * NN + i] + cnt4[3 * NN + i];
    sums[tid] = s;
    __syncthreads();
    for (int off = 1; off < 1024; off <<= 1) {
        int v = (tid >= off) ? sums[tid - off] : 0;
        __syncthreads();
        sums[tid] += v;
        __syncthreads();
    }
    int run = sums[tid] - s;              // exclusive prefix of this chunk
    for (int i = lo; i < hi; ++i) {
        row_ptr[i] = run;
        int c0 = cnt4[i], c1 = cnt4[NN + i], c2 = cnt4[2 * NN + i], c3 = cnt4[3 * NN + i];
        cursor4[i] = run;
        cursor4[NN + i] = run + c0;
        cursor4[2 * NN + i] = run + c0 + c1;
        cursor4[3 * NN + i] = run + c0 + c1 + c2;
        run += c0 + c1 + c2 + c3;
    }
    if (tid == 0) row_ptr[NN] = sums[1023];
}

// adjacency entry = (src, eid) packed int2 -> single 8B scatter store
__global__ void place_kernel(const int* __restrict__ src, const int* __restrict__ dst,
                             int* __restrict__ cursor4, int2* __restrict__ adj) {
    int i = blockIdx.x * blockDim.x + threadIdx.x;
    if (i < NE) {
        int d = dst[i];
        int pos = atomicAdd(&cursor4[(i / CHUNK) * NN + d], 1);
        adj[pos] = make_int2(src[i], i);
    }
}

// esum[v] = sum of incoming-edge features (round-invariant), CSR, no atomics.
// 4 lanes x float4 per edge, 16 edges in flight, unrolled x2.
__global__ __launch_bounds__(256) void esum_csr_kernel(
        const float* __restrict__ ef, const int* __restrict__ row_ptr,
        const int2* __restrict__ adj, float* __restrict__ esum,
        float* __restrict__ degf) {
    int wid = threadIdx.x >> 6, lane = threadIdx.x & 63;
    int v = blockIdx.x * 4 + wid;
    if (v >= NN) return;
    int rp0 = row_ptr[v], rp1 = row_ptr[v + 1];
    int q = lane >> 2;              // 0..15: edge slot
    int fo = (lane & 3) << 2;       // float4 feature offset
    float4 a0 = make_float4(0.f, 0.f, 0.f, 0.f), a1 = a0;
    int i = rp0 + q;
    for (; i + 16 < rp1; i += 32) {
        int e0 = adj[i].y, e1 = adj[i + 16].y;
        float4 x0 = *(const float4*)(ef + (size_t)e0 * 16 + fo);
        float4 x1 = *(const float4*)(ef + (size_t)e1 * 16 + fo);
        a0.x += x0.x; a0.y += x0.y; a0.z += x0.z; a0.w += x0.w;
        a1.x += x1.x; a1.y += x1.y; a1.z += x1.z; a1.w += x1.w;
    }
    for (; i < rp1; i += 16) {
        int e = adj[i].y;
        float4 x = *(const float4*)(ef + (size_t)e * 16 + fo);
        a0.x += x.x; a0.y += x.y; a0.z += x.z; a0.w += x.w;
    }
    a0.x += a1.x; a0.y += a1.y; a0.z += a1.z; a0.w += a1.w;
#pragma unroll
    for (int m = 4; m < 64; m <<= 1) {
        a0.x += __shfl_xor(a0.x, m);
        a0.y += __shfl_xor(a0.y, m);
        a0.z += __shfl_xor(a0.z, m);
        a0.w += __shfl_xor(a0.w, m);
    }
    if (lane < 4) *(float4*)(esum + (size_t)v * 16 + fo) = a0;
    if (lane == 0) degf[v] = (float)(rp1 - rp0);
}

// Fold: WcT[t][j][k] = sum_m W_msg[t][k][m] * W_ih[t][j][m]   (j<192, k<144)
//       bvec[t][j]   = sum_m b_msg[t][m]    * W_ih[t][j][m]
__global__ __launch_bounds__(192) void fold_kernel(
        const float* __restrict__ W_msg, const float* __restrict__ b_msg,
        const float* __restrict__ W_ih, float* __restrict__ WcT,
        float* __restrict__ bvec) {
    __shared__ float ldsW[64][193];   // [m-sub][j], padded
    int t = blockIdx.x / 9;
    int k0 = (blockIdx.x % 9) * 16;
    int j = threadIdx.x;
    float acc[16];
#pragma unroll
    for (int kk = 0; kk < 16; ++kk) acc[kk] = 0.f;
    float bacc = 0.f;
    for (int mc = 0; mc < 2; ++mc) {
        for (int i = threadIdx.x; i < 192 * 64; i += 192) {
            int jj = i >> 6, mm = i & 63;
            ldsW[mm][jj] = W_ih[((size_t)t * 192 + jj) * 128 + mc * 64 + mm];
        }
        __syncthreads();
        for (int mm = 0; mm < 64; ++mm) {
            float wl = ldsW[mm][j];
            float bm = b_msg[t * 128 + mc * 64 + mm];
            bacc = fmaf(bm, wl, bacc);
#pragma unroll
            for (int kk = 0; kk < 16; ++kk) {
                float wm = W_msg[((size_t)t * 144 + k0 + kk) * 128 + mc * 64 + mm];
                acc[kk] = fmaf(wm, wl, acc[kk]);
            }
        }
        __syncthreads();
    }
#pragma unroll
    for (int kk = 0; kk < 16; ++kk)
        WcT[((size_t)t * 192 + j) * 144 + k0 + kk] = acc[kk];
    if (k0 == 0) bvec[t * 192 + j] = bacc;
}

// ---------------- per-round ----------------
// Z[v] = [ deg(v)*hv[v] (64) | S[v]=sum hv[src] (64) | esum[v] (16) ]
__global__ __launch_bounds__(256) void gather_kernel(
        const float* __restrict__ hv, const float* __restrict__ esum,
        const int* __restrict__ row_ptr, const int2* __restrict__ adj,
        float* __restrict__ Z) {
    int wid = threadIdx.x >> 6, lane = threadIdx.x & 63;
    int v = blockIdx.x * 4 + wid;
    if (v >= NN) return;
    int rp0 = row_ptr[v], rp1 = row_ptr[v + 1];
    int q = lane >> 4;
    int fo = (lane & 15) << 2;
    float4 a0 = make_float4(0.f, 0.f, 0.f, 0.f), a1 = a0, a2 = a0, a3 = a0;
    int i = rp0 + q;
    for (; i + 12 < rp1; i += 16) {
        int s0 = adj[i].x;
        int s1 = adj[i + 4].x;
        int s2 = adj[i + 8].x;
        int s3 = adj[i + 12].x;
        float4 x0 = *(const float4*)(hv + (size_t)s0 * 64 + fo);
        float4 x1 = *(const float4*)(hv + (size_t)s1 * 64 + fo);
        float4 x2 = *(const float4*)(hv + (size_t)s2 * 64 + fo);
        float4 x3 = *(const float4*)(hv + (size_t)s3 * 64 + fo);
        a0.x += x0.x; a0.y += x0.y; a0.z += x0.z; a0.w += x0.w;
        a1.x += x1.x; a1.y += x1.y; a1.z += x1.z; a1.w += x1.w;
        a2.x += x2.x; a2.y += x2.y; a2.z += x2.z; a2.w += x2.w;
        a3.x += x3.x; a3.y += x3.y; a3.z += x3.z; a3.w += x3.w;
    }
    for (; i < rp1; i += 4) {
        int s = adj[i].x;
        float4 x = *(const float4*)(hv + (size_t)s * 64 + fo);
        a0.x += x.x; a0.y += x.y; a0.z += x.z; a0.w += x.w;
    }
    a0.x += a1.x + a2.x + a3.x;
    a0.y += a1.y + a2.y + a3.y;
    a0.z += a1.z + a2.z + a3.z;
    a0.w += a1.w + a2.w + a3.w;
#pragma unroll
    for (int m = 16; m < 64; m <<= 1) {
        a0.x += __shfl_xor(a0.x, m);
        a0.y += __shfl_xor(a0.y, m);
        a0.z += __shfl_xor(a0.z, m);
        a0.w += __shfl_xor(a0.w, m);
    }
    float dg = (float)(rp1 - rp0);
    if (lane < 16) {
        float4 hvv = *(const float4*)(hv + (size_t)v * 64 + fo);
        float4 zh = make_float4(dg * hvv.x, dg * hvv.y, dg * hvv.z, dg * hvv.w);
        *(float4*)(Z + (size_t)v * 144 + fo) = zh;
        *(float4*)(Z + (size_t)v * 144 + 64 + fo) = a0;
    } else if (lane < 20) {
        int f2 = (lane - 16) << 2;
        *(float4*)(Z + (size_t)v * 144 + 128 + f2) =
            *(const float4*)(esum + (size_t)v * 16 + f2);
    }
}

// C[M,N] = A[M,K] @ B[N,K]^T + bias_s[n]*bscale[m] + bias_f[n]
__global__ __launch_bounds__(256) void gemm_abt(
    const float* __restrict__ A, const float* __restrict__ B,
    const float* __restrict__ bias_s, const float* __restrict__ bscale,
    const float* __restrict__ bias_f,
    float* __restrict__ C, int M, int N, int K) {
    const int BK = 32;
    __shared__ float As[32][132];
    __shared__ float Bs[32][68];
    int tid = threadIdx.x;
    int ty = tid >> 4, tx = tid & 15;
    int row0 = blockIdx.x * 128;
    int col0 = blockIdx.y * 64;
    float acc[8][4];
#pragma unroll
    for (int i = 0; i < 8; ++i)
#pragma unroll
        for (int j = 0; j < 4; ++j) acc[i][j] = 0.f;

    int lr = tid >> 3;
    int lk = (tid & 7) << 2;

    for (int k0 = 0; k0 < K; k0 += BK) {
#pragma unroll
        for (int p = 0; p < 4; ++p) {
            int r = lr + p * 32;
            float4 v = make_float4(0.f, 0.f, 0.f, 0.f);
            int gr = row0 + r, gk = k0 + lk;
            if (gr < M && gk < K) v = *(const float4*)(A + (size_t)gr * K + gk);
            As[lk + 0][r] = v.x; As[lk + 1][r] = v.y;
            As[lk + 2][r] = v.z; As[lk + 3][r] = v.w;
        }
#pragma unroll
        for (int p = 0; p < 2; ++p) {
            int n = lr + p * 32;
            float4 v = make_float4(0.f, 0.f, 0.f, 0.f);
            int gk = k0 + lk;
            if (gk < K) v = *(const float4*)(B + (size_t)(col0 + n) * K + gk);
            Bs[lk + 0][n] = v.x; Bs[lk + 1][n] = v.y;
            Bs[lk + 2][n] = v.z; Bs[lk + 3][n] = v.w;
        }
        __syncthreads();
#pragma unroll
        for (int kk = 0; kk < BK; ++kk) {
            float4 a0 = *(const float4*)&As[kk][ty * 8];
            float4 a1 = *(const float4*)&As[kk][ty * 8 + 4];
            float4 b0 = *(const float4*)&Bs[kk][tx * 4];
            float av[8] = {a0.x, a0.y, a0.z, a0.w, a1.x, a1.y, a1.z, a1.w};
            float bv[4] = {b0.x, b0.y, b0.z, b0.w};
#pragma unroll
            for (int i = 0; i < 8; ++i)
#pragma unroll
                for (int j = 0; j < 4; ++j)
                    acc[i][j] = fmaf(av[i], bv[j], acc[i][j]);
        }
        __syncthreads();
    }

    int c = col0 + tx * 4;
#pragma unroll
    for (int i = 0; i < 8; ++i) {
        int r = row0 + ty * 8 + i;
        if (r >= M) continue;
        float bs = bscale[r];
        float4 o;
        o.x = acc[i][0] + bias_s[c + 0] * bs + bias_f[c + 0];
        o.y = acc[i][1] + bias_s[c + 1] * bs + bias_f[c + 1];
        o.z = acc[i][2] + bias_s[c + 2] * bs + bias_f[c + 2];
        o.w = acc[i][3] + bias_s[c + 3] * bs + bias_f[c + 3];
        *(float4*)(C + (size_t)r * N + c) = o;
    }
}

// Fused gh-GEMM + GRU gates.
__global__ __launch_bounds__(256) void gru_fused_kernel(
        const float* __restrict__ gi, const float* __restrict__ hin,
        const float* __restrict__ W_hh, const float* __restrict__ b_hh,
        float* __restrict__ out) {
    __shared__ float Wt[64][193];
    __shared__ float bh[192];
    __shared__ float hrow[4][64];
    for (int i = threadIdx.x; i < 192 * 64; i += 256) {
        int j = i >> 6, k = i & 63;
        Wt[k][j] = W_hh[i];
    }
    if (threadIdx.x < 192) bh[threadIdx.x] = b_hh[threadIdx.x];
    __syncthreads();
    int wid = threadIdx.x >> 6, lane = threadIdx.x & 63;
    for (int row = blockIdx.x * 4 + wid; row < NN; row += gridDim.x * 4) {
        float h = hin[(size_t)row * 64 + lane];
        const float* gim = gi + (size_t)row * 192;
        float gr = gim[lane], gz = gim[64 + lane], gn = gim[128 + lane];
        hrow[wid][lane] = h;
        float ar = 0.f, az = 0.f, an = 0.f;
#pragma unroll
        for (int k = 0; k < 64; ++k) {
            float hk = hrow[wid][k];
            ar = fmaf(hk, Wt[k][lane], ar);
            az = fmaf(hk, Wt[k][64 + lane], az);
            an = fmaf(hk, Wt[k][128 + lane], an);
        }
        float r = 1.f / (1.f + __expf(-(gr + ar + bh[lane])));
        float z = 1.f / (1.f + __expf(-(gz + az + bh[64 + lane])));
        float n = tanhf(gn + r * (an + bh[128 + lane]));
        out[(size_t)row * 64 + lane] = (1.f - z) * n + z * h;
    }
}

extern "C" void kernel_launch(void* const* d_in, const int* in_sizes, int n_in,
                              void* d_out, int out_size, void* d_ws, size_t ws_size,
                              hipStream_t stream) {
    const float* hv0   = (const float*)d_in[0];
    const float* ef    = (const float*)d_in[1];
    const int*   src   = (const int*)d_in[2];
    const int*   dst   = (const int*)d_in[3];
    const float* W_msg = (const float*)d_in[4];
    const float* b_msg = (const float*)d_in[5];
    const float* W_ih  = (const float*)d_in[6];
    const float* W_hh  = (const float*)d_in[7];
    const float* b_ih  = (const float*)d_in[8];
    const float* b_hh  = (const float*)d_in[9];
    float* out = (float*)d_out;

    char* ws = (char*)d_ws;
    size_t off = 0;
    auto alloc = [&](size_t bytes) -> char* {
        char* p = ws + off;
        off = (off + bytes + 255) & ~(size_t)255;
        return p;
    };
    int*   cnt4    = (int*)alloc((size_t)NC * NN * 4);
    int*   row_ptr = (int*)alloc((NN + 1) * 4);
    int*   cursor4 = (int*)alloc((size_t)NC * NN * 4);
    int2*  adj     = (int2*)alloc((size_t)NE * 8);
    float* esum    = (float*)alloc((size_t)NN * 16 * 4);
    float* degf    = (float*)alloc(NN * 4);
    float* Z       = (float*)alloc((size_t)NN * 144 * 4);
    float* gi      = (float*)alloc((size_t)NN * 192 * 4);
    float* hv1     = (float*)alloc((size_t)NN * 64 * 4);
    float* WcT     = (float*)alloc((size_t)2 * 192 * 144 * 4);
    float* bvec    = (float*)alloc(2 * 192 * 4);

    zero_kernel<<<(NC * NN + 1023) / 1024, 1024, 0, stream>>>(cnt4, NC * NN);
    hist_kernel<<<(NE + 255) / 256, 256, 0, stream>>>(dst, cnt4);
    scan_kernel<<<1, 1024, 0, stream>>>(cnt4, row_ptr, cursor4);
    place_kernel<<<(NE + 255) / 256, 256, 0, stream>>>(src, dst, cursor4, adj);
    esum_csr_kernel<<<(NN + 3) / 4, 256, 0, stream>>>(ef, row_ptr, adj, esum, degf);
    fold_kernel<<<18, 192, 0, stream>>>(W_msg, b_msg, W_ih, WcT, bvec);

    for (int t = 0; t < 2; ++t) {
        const float* hin = (t == 0) ? hv0 : hv1;
        float* hout = (t == 1) ? out : hv1;
        gather_kernel<<<(NN + 3) / 4, 256, 0, stream>>>(hin, esum, row_ptr, adj, Z);
        dim3 g1((NN + 127) / 128, 3);
        gemm_abt<<<g1, 256, 0, stream>>>(Z, WcT + (size_t)t * 192 * 144,
                                         bvec + t * 192, degf, b_ih + (size_t)t * 192,
                                         gi, NN, 192, 144);
        gru_fused_kernel<<<256, 256, 0, stream>>>(gi, hin, W_hh + (size_t)t * 192 * 64,
                                                  b_hh + t * 192, hout);
    }
}

// Round 4
// 269.657 us; speedup vs baseline: 1.3293x; 1.3293x over previous
//
#include <hip/hip_runtime.h>
#include <cstddef>
#include <cstdint>

#define NN 20000
#define NE 640000
#define HD 64
#define NC 4
#define CHUNK 160000   // NE / NC
#define NB_SCAN 79     // ceil(NN/256)

// ---------------- CSR build ----------------
__global__ void zero_kernel(int* __restrict__ p, int n) {
    int i = blockIdx.x * blockDim.x + threadIdx.x;
    if (i < n) p[i] = 0;
}

// chunked histogram: cnt4[c][v], c = edge_index / CHUNK  (contention depth /4)
__global__ void hist_kernel(const int* __restrict__ dst, int* __restrict__ cnt4) {
    int i = blockIdx.x * blockDim.x + threadIdx.x;
    if (i < NE) atomicAdd(&cnt4[(i / CHUNK) * NN + dst[i]], 1);
}

// hierarchical scan, stage 1: per-block exclusive prefix of node degrees
__global__ __launch_bounds__(256) void scan1_kernel(const int* __restrict__ cnt4,
                                                    int* __restrict__ lp,
                                                    int* __restrict__ bsum) {
    __shared__ int s[256];
    int t = threadIdx.x;
    int i = blockIdx.x * 256 + t;
    int d = 0;
    if (i < NN) d = cnt4[i] + cnt4[NN + i] + cnt4[2 * NN + i] + cnt4[3 * NN + i];
    s[t] = d;
    __syncthreads();
    for (int off = 1; off < 256; off <<= 1) {
        int v = (t >= off) ? s[t - off] : 0;
        __syncthreads();
        s[t] += v;
        __syncthreads();
    }
    if (i < NN) lp[i] = s[t] - d;           // local exclusive prefix
    if (t == 255) bsum[blockIdx.x] = s[255];
}

// stage 2: scan the 79 block sums (one tiny block)
__global__ __launch_bounds__(128) void scan2_kernel(const int* __restrict__ bsum,
                                                    int* __restrict__ boff) {
    __shared__ int s[128];
    int t = threadIdx.x;
    int v = (t < NB_SCAN) ? bsum[t] : 0;
    s[t] = v;
    __syncthreads();
    for (int off = 1; off < 128; off <<= 1) {
        int u = (t >= off) ? s[t - off] : 0;
        __syncthreads();
        s[t] += u;
        __syncthreads();
    }
    if (t < NB_SCAN) boff[t] = s[t] - v;    // exclusive block offset
}

// stage 3: emit row_ptr and the 4 chunk cursors
__global__ __launch_bounds__(256) void scan3_kernel(const int* __restrict__ cnt4,
                                                    const int* __restrict__ lp,
                                                    const int* __restrict__ boff,
                                                    int* __restrict__ row_ptr,
                                                    int* __restrict__ cursor4) {
    int i = blockIdx.x * 256 + threadIdx.x;
    if (i < NN) {
        int base = boff[blockIdx.x] + lp[i];
        row_ptr[i] = base;
        int c0 = cnt4[i], c1 = cnt4[NN + i], c2 = cnt4[2 * NN + i];
        cursor4[i] = base;
        cursor4[NN + i] = base + c0;
        cursor4[2 * NN + i] = base + c0 + c1;
        cursor4[3 * NN + i] = base + c0 + c1 + c2;
    }
    if (i == 0) row_ptr[NN] = NE;           // total is known statically
}

// adjacency entry = (src, eid) packed int2 -> single 8B scatter store
__global__ void place_kernel(const int* __restrict__ src, const int* __restrict__ dst,
                             int* __restrict__ cursor4, int2* __restrict__ adj) {
    int i = blockIdx.x * blockDim.x + threadIdx.x;
    if (i < NE) {
        int d = dst[i];
        int pos = atomicAdd(&cursor4[(i / CHUNK) * NN + d], 1);
        adj[pos] = make_int2(src[i], i);
    }
}

// esum[v] = sum of incoming-edge features (round-invariant), CSR, no atomics.
__global__ __launch_bounds__(256) void esum_csr_kernel(
        const float* __restrict__ ef, const int* __restrict__ row_ptr,
        const int2* __restrict__ adj, float* __restrict__ esum,
        float* __restrict__ degf) {
    int wid = threadIdx.x >> 6, lane = threadIdx.x & 63;
    int v = blockIdx.x * 4 + wid;
    if (v >= NN) return;
    int rp0 = row_ptr[v], rp1 = row_ptr[v + 1];
    int q = lane >> 2;              // 0..15: edge slot
    int fo = (lane & 3) << 2;       // float4 feature offset
    float4 a0 = make_float4(0.f, 0.f, 0.f, 0.f), a1 = a0;
    int i = rp0 + q;
    for (; i + 16 < rp1; i += 32) {
        int e0 = adj[i].y, e1 = adj[i + 16].y;
        float4 x0 = *(const float4*)(ef + (size_t)e0 * 16 + fo);
        float4 x1 = *(const float4*)(ef + (size_t)e1 * 16 + fo);
        a0.x += x0.x; a0.y += x0.y; a0.z += x0.z; a0.w += x0.w;
        a1.x += x1.x; a1.y += x1.y; a1.z += x1.z; a1.w += x1.w;
    }
    for (; i < rp1; i += 16) {
        int e = adj[i].y;
        float4 x = *(const float4*)(ef + (size_t)e * 16 + fo);
        a0.x += x.x; a0.y += x.y; a0.z += x.z; a0.w += x.w;
    }
    a0.x += a1.x; a0.y += a1.y; a0.z += a1.z; a0.w += a1.w;
#pragma unroll
    for (int m = 4; m < 64; m <<= 1) {
        a0.x += __shfl_xor(a0.x, m);
        a0.y += __shfl_xor(a0.y, m);
        a0.z += __shfl_xor(a0.z, m);
        a0.w += __shfl_xor(a0.w, m);
    }
    if (lane < 4) *(float4*)(esum + (size_t)v * 16 + fo) = a0;
    if (lane == 0) degf[v] = (float)(rp1 - rp0);
}

// Fold: WcT[t][j][k] = sum_m W_msg[t][k][m] * W_ih[t][j][m]   (j<192, k<144)
//       bvec[t][j]   = sum_m b_msg[t][m]    * W_ih[t][j][m]
__global__ __launch_bounds__(192) void fold_kernel(
        const float* __restrict__ W_msg, const float* __restrict__ b_msg,
        const float* __restrict__ W_ih, float* __restrict__ WcT,
        float* __restrict__ bvec) {
    __shared__ float ldsW[64][193];   // [m-sub][j], padded
    int t = blockIdx.x / 9;
    int k0 = (blockIdx.x % 9) * 16;
    int j = threadIdx.x;
    float acc[16];
#pragma unroll
    for (int kk = 0; kk < 16; ++kk) acc[kk] = 0.f;
    float bacc = 0.f;
    for (int mc = 0; mc < 2; ++mc) {
        for (int i = threadIdx.x; i < 192 * 64; i += 192) {
            int jj = i >> 6, mm = i & 63;
            ldsW[mm][jj] = W_ih[((size_t)t * 192 + jj) * 128 + mc * 64 + mm];
        }
        __syncthreads();
        for (int mm = 0; mm < 64; ++mm) {
            float wl = ldsW[mm][j];
            float bm = b_msg[t * 128 + mc * 64 + mm];
            bacc = fmaf(bm, wl, bacc);
#pragma unroll
            for (int kk = 0; kk < 16; ++kk) {
                float wm = W_msg[((size_t)t * 144 + k0 + kk) * 128 + mc * 64 + mm];
                acc[kk] = fmaf(wm, wl, acc[kk]);
            }
        }
        __syncthreads();
    }
#pragma unroll
    for (int kk = 0; kk < 16; ++kk)
        WcT[((size_t)t * 192 + j) * 144 + k0 + kk] = acc[kk];
    if (k0 == 0) bvec[t * 192 + j] = bacc;
}

// ---------------- per-round ----------------
// Z[v] = [ deg(v)*hv[v] (64) | S[v]=sum hv[src] (64) | esum[v] (16) ]
__global__ __launch_bounds__(256) void gather_kernel(
        const float* __restrict__ hv, const float* __restrict__ esum,
        const int* __restrict__ row_ptr, const int2* __restrict__ adj,
        float* __restrict__ Z) {
    int wid = threadIdx.x >> 6, lane = threadIdx.x & 63;
    int v = blockIdx.x * 4 + wid;
    if (v >= NN) return;
    int rp0 = row_ptr[v], rp1 = row_ptr[v + 1];
    int q = lane >> 4;
    int fo = (lane & 15) << 2;
    float4 a0 = make_float4(0.f, 0.f, 0.f, 0.f), a1 = a0, a2 = a0, a3 = a0;
    int i = rp0 + q;
    for (; i + 12 < rp1; i += 16) {
        int s0 = adj[i].x;
        int s1 = adj[i + 4].x;
        int s2 = adj[i + 8].x;
        int s3 = adj[i + 12].x;
        float4 x0 = *(const float4*)(hv + (size_t)s0 * 64 + fo);
        float4 x1 = *(const float4*)(hv + (size_t)s1 * 64 + fo);
        float4 x2 = *(const float4*)(hv + (size_t)s2 * 64 + fo);
        float4 x3 = *(const float4*)(hv + (size_t)s3 * 64 + fo);
        a0.x += x0.x; a0.y += x0.y; a0.z += x0.z; a0.w += x0.w;
        a1.x += x1.x; a1.y += x1.y; a1.z += x1.z; a1.w += x1.w;
        a2.x += x2.x; a2.y += x2.y; a2.z += x2.z; a2.w += x2.w;
        a3.x += x3.x; a3.y += x3.y; a3.z += x3.z; a3.w += x3.w;
    }
    for (; i < rp1; i += 4) {
        int s = adj[i].x;
        float4 x = *(const float4*)(hv + (size_t)s * 64 + fo);
        a0.x += x.x; a0.y += x.y; a0.z += x.z; a0.w += x.w;
    }
    a0.x += a1.x + a2.x + a3.x;
    a0.y += a1.y + a2.y + a3.y;
    a0.z += a1.z + a2.z + a3.z;
    a0.w += a1.w + a2.w + a3.w;
#pragma unroll
    for (int m = 16; m < 64; m <<= 1) {
        a0.x += __shfl_xor(a0.x, m);
        a0.y += __shfl_xor(a0.y, m);
        a0.z += __shfl_xor(a0.z, m);
        a0.w += __shfl_xor(a0.w, m);
    }
    float dg = (float)(rp1 - rp0);
    if (lane < 16) {
        float4 hvv = *(const float4*)(hv + (size_t)v * 64 + fo);
        float4 zh = make_float4(dg * hvv.x, dg * hvv.y, dg * hvv.z, dg * hvv.w);
        *(float4*)(Z + (size_t)v * 144 + fo) = zh;
        *(float4*)(Z + (size_t)v * 144 + 64 + fo) = a0;
    } else if (lane < 20) {
        int f2 = (lane - 16) << 2;
        *(float4*)(Z + (size_t)v * 144 + 128 + f2) =
            *(const float4*)(esum + (size_t)v * 16 + f2);
    }
}

// C[M,N] = A[M,K] @ B[N,K]^T + bias_s[n]*bscale[m] + bias_f[n]
__global__ __launch_bounds__(256) void gemm_abt(
    const float* __restrict__ A, const float* __restrict__ B,
    const float* __restrict__ bias_s, const float* __restrict__ bscale,
    const float* __restrict__ bias_f,
    float* __restrict__ C, int M, int N, int K) {
    const int BK = 32;
    __shared__ float As[32][132];
    __shared__ float Bs[32][68];
    int tid = threadIdx.x;
    int ty = tid >> 4, tx = tid & 15;
    int row0 = blockIdx.x * 128;
    int col0 = blockIdx.y * 64;
    float acc[8][4];
#pragma unroll
    for (int i = 0; i < 8; ++i)
#pragma unroll
        for (int j = 0; j < 4; ++j) acc[i][j] = 0.f;

    int lr = tid >> 3;
    int lk = (tid & 7) << 2;

    for (int k0 = 0; k0 < K; k0 += BK) {
#pragma unroll
        for (int p = 0; p < 4; ++p) {
            int r = lr + p * 32;
            float4 v = make_float4(0.f, 0.f, 0.f, 0.f);
            int gr = row0 + r, gk = k0 + lk;
            if (gr < M && gk < K) v = *(const float4*)(A + (size_t)gr * K + gk);
            As[lk + 0][r] = v.x; As[lk + 1][r] = v.y;
            As[lk + 2][r] = v.z; As[lk + 3][r] = v.w;
        }
#pragma unroll
        for (int p = 0; p < 2; ++p) {
            int n = lr + p * 32;
            float4 v = make_float4(0.f, 0.f, 0.f, 0.f);
            int gk = k0 + lk;
            if (gk < K) v = *(const float4*)(B + (size_t)(col0 + n) * K + gk);
            Bs[lk + 0][n] = v.x; Bs[lk + 1][n] = v.y;
            Bs[lk + 2][n] = v.z; Bs[lk + 3][n] = v.w;
        }
        __syncthreads();
#pragma unroll
        for (int kk = 0; kk < BK; ++kk) {
            float4 a0 = *(const float4*)&As[kk][ty * 8];
            float4 a1 = *(const float4*)&As[kk][ty * 8 + 4];
            float4 b0 = *(const float4*)&Bs[kk][tx * 4];
            float av[8] = {a0.x, a0.y, a0.z, a0.w, a1.x, a1.y, a1.z, a1.w};
            float bv[4] = {b0.x, b0.y, b0.z, b0.w};
#pragma unroll
            for (int i = 0; i < 8; ++i)
#pragma unroll
                for (int j = 0; j < 4; ++j)
                    acc[i][j] = fmaf(av[i], bv[j], acc[i][j]);
        }
        __syncthreads();
    }

    int c = col0 + tx * 4;
#pragma unroll
    for (int i = 0; i < 8; ++i) {
        int r = row0 + ty * 8 + i;
        if (r >= M) continue;
        float bs = bscale[r];
        float4 o;
        o.x = acc[i][0] + bias_s[c + 0] * bs + bias_f[c + 0];
        o.y = acc[i][1] + bias_s[c + 1] * bs + bias_f[c + 1];
        o.z = acc[i][2] + bias_s[c + 2] * bs + bias_f[c + 2];
        o.w = acc[i][3] + bias_s[c + 3] * bs + bias_f[c + 3];
        *(float4*)(C + (size_t)r * N + c) = o;
    }
}

// Fused gh-GEMM + GRU gates.
__global__ __launch_bounds__(256) void gru_fused_kernel(
        const float* __restrict__ gi, const float* __restrict__ hin,
        const float* __restrict__ W_hh, const float* __restrict__ b_hh,
        float* __restrict__ out) {
    __shared__ float Wt[64][193];
    __shared__ float bh[192];
    __shared__ float hrow[4][64];
    for (int i = threadIdx.x; i < 192 * 64; i += 256) {
        int j = i >> 6, k = i & 63;
        Wt[k][j] = W_hh[i];
    }
    if (threadIdx.x < 192) bh[threadIdx.x] = b_hh[threadIdx.x];
    __syncthreads();
    int wid = threadIdx.x >> 6, lane = threadIdx.x & 63;
    for (int row = blockIdx.x * 4 + wid; row < NN; row += gridDim.x * 4) {
        float h = hin[(size_t)row * 64 + lane];
        const float* gim = gi + (size_t)row * 192;
        float gr = gim[lane], gz = gim[64 + lane], gn = gim[128 + lane];
        hrow[wid][lane] = h;
        float ar = 0.f, az = 0.f, an = 0.f;
#pragma unroll
        for (int k = 0; k < 64; ++k) {
            float hk = hrow[wid][k];
            ar = fmaf(hk, Wt[k][lane], ar);
            az = fmaf(hk, Wt[k][64 + lane], az);
            an = fmaf(hk, Wt[k][128 + lane], an);
        }
        float r = 1.f / (1.f + __expf(-(gr + ar + bh[lane])));
        float z = 1.f / (1.f + __expf(-(gz + az + bh[64 + lane])));
        float n = tanhf(gn + r * (an + bh[128 + lane]));
        out[(size_t)row * 64 + lane] = (1.f - z) * n + z * h;
    }
}

extern "C" void kernel_launch(void* const* d_in, const int* in_sizes, int n_in,
                              void* d_out, int out_size, void* d_ws, size_t ws_size,
                              hipStream_t stream) {
    const float* hv0   = (const float*)d_in[0];
    const float* ef    = (const float*)d_in[1];
    const int*   src   = (const int*)d_in[2];
    const int*   dst   = (const int*)d_in[3];
    const float* W_msg = (const float*)d_in[4];
    const float* b_msg = (const float*)d_in[5];
    const float* W_ih  = (const float*)d_in[6];
    const float* W_hh  = (const float*)d_in[7];
    const float* b_ih  = (const float*)d_in[8];
    const float* b_hh  = (const float*)d_in[9];
    float* out = (float*)d_out;

    char* ws = (char*)d_ws;
    size_t off = 0;
    auto alloc = [&](size_t bytes) -> char* {
        char* p = ws + off;
        off = (off + bytes + 255) & ~(size_t)255;
        return p;
    };
    int*   cnt4    = (int*)alloc((size_t)NC * NN * 4);
    int*   row_ptr = (int*)alloc((NN + 1) * 4);
    int*   cursor4 = (int*)alloc((size_t)NC * NN * 4);
    int2*  adj     = (int2*)alloc((size_t)NE * 8);
    float* esum    = (float*)alloc((size_t)NN * 16 * 4);
    float* degf    = (float*)alloc(NN * 4);
    float* Z       = (float*)alloc((size_t)NN * 144 * 4);
    float* gi      = (float*)alloc((size_t)NN * 192 * 4);
    float* hv1     = (float*)alloc((size_t)NN * 64 * 4);
    float* WcT     = (float*)alloc((size_t)2 * 192 * 144 * 4);
    float* bvec    = (float*)alloc(2 * 192 * 4);
    int*   lp      = (int*)alloc(NN * 4);
    int*   bsum    = (int*)alloc(NB_SCAN * 4);
    int*   boff    = (int*)alloc(NB_SCAN * 4);

    zero_kernel<<<(NC * NN + 1023) / 1024, 1024, 0, stream>>>(cnt4, NC * NN);
    hist_kernel<<<(NE + 255) / 256, 256, 0, stream>>>(dst, cnt4);
    scan1_kernel<<<NB_SCAN, 256, 0, stream>>>(cnt4, lp, bsum);
    scan2_kernel<<<1, 128, 0, stream>>>(bsum, boff);
    scan3_kernel<<<NB_SCAN, 256, 0, stream>>>(cnt4, lp, boff, row_ptr, cursor4);
    place_kernel<<<(NE + 255) / 256, 256, 0, stream>>>(src, dst, cursor4, adj);
    esum_csr_kernel<<<(NN + 3) / 4, 256, 0, stream>>>(ef, row_ptr, adj, esum, degf);
    fold_kernel<<<18, 192, 0, stream>>>(W_msg, b_msg, W_ih, WcT, bvec);

    for (int t = 0; t < 2; ++t) {
        const float* hin = (t == 0) ? hv0 : hv1;
        float* hout = (t == 1) ? out : hv1;
        gather_kernel<<<(NN + 3) / 4, 256, 0, stream>>>(hin, esum, row_ptr, adj, Z);
        dim3 g1((NN + 127) / 128, 3);
        gemm_abt<<<g1, 256, 0, stream>>>(Z, WcT + (size_t)t * 192 * 144,
                                         bvec + t * 192, degf, b_ih + (size_t)t * 192,
                                         gi, NN, 192, 144);
        gru_fused_kernel<<<256, 256, 0, stream>>>(gi, hin, W_hh + (size_t)t * 192 * 64,
                                                  b_hh + t * 192, hout);
    }
}

// Round 6
// 258.509 us; speedup vs baseline: 1.3866x; 1.0431x over previous
//
#include <hip/hip_runtime.h>
#include <hip/hip_fp16.h>
#include <cstddef>
#include <cstdint>

#define NN 20000
#define NE 640000
#define HD 64
#define NC 4
#define CHUNK 160000   // NE / NC
#define NB_SCAN 79     // ceil(NN/256)

__device__ __forceinline__ float h2f(unsigned short u) {
    __half h;
    *reinterpret_cast<unsigned short*>(&h) = u;
    return __half2float(h);
}

// ---------------- setup ----------------
__global__ void zero_kernel(int* __restrict__ p, int n) {
    int i = blockIdx.x * blockDim.x + threadIdx.x;
    if (i < n) p[i] = 0;
}

__global__ void tohf_kernel(const float* __restrict__ in, __half* __restrict__ out, int n) {
    int i = blockIdx.x * blockDim.x + threadIdx.x;
    if (i < n) out[i] = __float2half(in[i]);
}

// chunked histogram: cnt4[c][v], c = edge_index / CHUNK
__global__ void hist_kernel(const int* __restrict__ dst, int* __restrict__ cnt4) {
    int i = blockIdx.x * blockDim.x + threadIdx.x;
    if (i < NE) atomicAdd(&cnt4[(i / CHUNK) * NN + dst[i]], 1);
}

__global__ __launch_bounds__(256) void scan1_kernel(const int* __restrict__ cnt4,
                                                    int* __restrict__ lp,
                                                    int* __restrict__ bsum) {
    __shared__ int s[256];
    int t = threadIdx.x;
    int i = blockIdx.x * 256 + t;
    int d = 0;
    if (i < NN) d = cnt4[i] + cnt4[NN + i] + cnt4[2 * NN + i] + cnt4[3 * NN + i];
    s[t] = d;
    __syncthreads();
    for (int off = 1; off < 256; off <<= 1) {
        int v = (t >= off) ? s[t - off] : 0;
        __syncthreads();
        s[t] += v;
        __syncthreads();
    }
    if (i < NN) lp[i] = s[t] - d;
    if (t == 255) bsum[blockIdx.x] = s[255];
}

__global__ __launch_bounds__(128) void scan2_kernel(const int* __restrict__ bsum,
                                                    int* __restrict__ boff) {
    __shared__ int s[128];
    int t = threadIdx.x;
    int v = (t < NB_SCAN) ? bsum[t] : 0;
    s[t] = v;
    __syncthreads();
    for (int off = 1; off < 128; off <<= 1) {
        int u = (t >= off) ? s[t - off] : 0;
        __syncthreads();
        s[t] += u;
        __syncthreads();
    }
    if (t < NB_SCAN) boff[t] = s[t] - v;
}

__global__ __launch_bounds__(256) void scan3_kernel(const int* __restrict__ cnt4,
                                                    const int* __restrict__ lp,
                                                    const int* __restrict__ boff,
                                                    int* __restrict__ row_ptr,
                                                    int* __restrict__ cursor4) {
    int i = blockIdx.x * 256 + threadIdx.x;
    if (i < NN) {
        int base = boff[blockIdx.x] + lp[i];
        row_ptr[i] = base;
        int c0 = cnt4[i], c1 = cnt4[NN + i], c2 = cnt4[2 * NN + i];
        cursor4[i] = base;
        cursor4[NN + i] = base + c0;
        cursor4[2 * NN + i] = base + c0 + c1;
        cursor4[3 * NN + i] = base + c0 + c1 + c2;
    }
    if (i == 0) row_ptr[NN] = NE;
}

__global__ void place_kernel(const int* __restrict__ src, const int* __restrict__ dst,
                             int* __restrict__ cursor4, int2* __restrict__ adj) {
    int i = blockIdx.x * blockDim.x + threadIdx.x;
    if (i < NE) {
        int d = dst[i];
        int pos = atomicAdd(&cursor4[(i / CHUNK) * NN + d], 1);
        adj[pos] = make_int2(src[i], i);
    }
}

// esum[v] = sum of incoming-edge features (round-invariant); also degf.
__global__ __launch_bounds__(256) void esum_csr_kernel(
        const float* __restrict__ ef, const int* __restrict__ row_ptr,
        const int2* __restrict__ adj, float* __restrict__ esum,
        float* __restrict__ degf) {
    int wid = threadIdx.x >> 6, lane = threadIdx.x & 63;
    int v = blockIdx.x * 4 + wid;
    if (v >= NN) return;
    int rp0 = row_ptr[v], rp1 = row_ptr[v + 1];
    int q = lane >> 2;
    int fo = (lane & 3) << 2;
    float4 a0 = make_float4(0.f, 0.f, 0.f, 0.f), a1 = a0;
    int i = rp0 + q;
    for (; i + 16 < rp1; i += 32) {
        int e0 = adj[i].y, e1 = adj[i + 16].y;
        float4 x0 = *(const float4*)(ef + (size_t)e0 * 16 + fo);
        float4 x1 = *(const float4*)(ef + (size_t)e1 * 16 + fo);
        a0.x += x0.x; a0.y += x0.y; a0.z += x0.z; a0.w += x0.w;
        a1.x += x1.x; a1.y += x1.y; a1.z += x1.z; a1.w += x1.w;
    }
    for (; i < rp1; i += 16) {
        int e = adj[i].y;
        float4 x = *(const float4*)(ef + (size_t)e * 16 + fo);
        a0.x += x.x; a0.y += x.y; a0.z += x.z; a0.w += x.w;
    }
    a0.x += a1.x; a0.y += a1.y; a0.z += a1.z; a0.w += a1.w;
#pragma unroll
    for (int m = 4; m < 64; m <<= 1) {
        a0.x += __shfl_xor(a0.x, m);
        a0.y += __shfl_xor(a0.y, m);
        a0.z += __shfl_xor(a0.z, m);
        a0.w += __shfl_xor(a0.w, m);
    }
    if (lane < 4) *(float4*)(esum + (size_t)v * 16 + fo) = a0;
    if (lane == 0) degf[v] = (float)(rp1 - rp0);
}

// Fold: WcT[t][j][k] = sum_m W_msg[t][k][m] * W_ih[t][j][m]   (j<192, k<144)
//       bvec[t][j]   = sum_m b_msg[t][m]    * W_ih[t][j][m]
__global__ __launch_bounds__(192) void fold_kernel(
        const float* __restrict__ W_msg, const float* __restrict__ b_msg,
        const float* __restrict__ W_ih, float* __restrict__ WcT,
        float* __restrict__ bvec) {
    __shared__ float ldsW[64][193];
    int t = blockIdx.x / 9;
    int k0 = (blockIdx.x % 9) * 16;
    int j = threadIdx.x;
    float acc[16];
#pragma unroll
    for (int kk = 0; kk < 16; ++kk) acc[kk] = 0.f;
    float bacc = 0.f;
    for (int mc = 0; mc < 2; ++mc) {
        for (int i = threadIdx.x; i < 192 * 64; i += 192) {
            int jj = i >> 6, mm = i & 63;
            ldsW[mm][jj] = W_ih[((size_t)t * 192 + jj) * 128 + mc * 64 + mm];
        }
        __syncthreads();
        for (int mm = 0; mm < 64; ++mm) {
            float wl = ldsW[mm][j];
            float bm = b_msg[t * 128 + mc * 64 + mm];
            bacc = fmaf(bm, wl, bacc);
#pragma unroll
            for (int kk = 0; kk < 16; ++kk) {
                float wm = W_msg[((size_t)t * 144 + k0 + kk) * 128 + mc * 64 + mm];
                acc[kk] = fmaf(wm, wl, acc[kk]);
            }
        }
        __syncthreads();
    }
#pragma unroll
    for (int kk = 0; kk < 16; ++kk)
        WcT[((size_t)t * 192 + j) * 144 + k0 + kk] = acc[kk];
    if (k0 == 0) bvec[t * 192 + j] = bacc;
}

// bias_row[t][v][j] = b_ih[t][j] + bvec[t][j]*deg[v] + sum_k esum[v][k]*WcT[t][j][128+k]
__global__ __launch_bounds__(192) void biasrow_kernel(
        const float* __restrict__ WcT, const float* __restrict__ bvec,
        const float* __restrict__ b_ih, const float* __restrict__ esum,
        const float* __restrict__ degf, float* __restrict__ bias_row) {
    int t = blockIdx.y;
    int j = threadIdx.x;
    int r0 = blockIdx.x * 128;
    float wj[16];
#pragma unroll
    for (int k = 0; k < 16; ++k)
        wj[k] = WcT[((size_t)t * 192 + j) * 144 + 128 + k];
    float bj = bvec[t * 192 + j];
    float bc = b_ih[t * 192 + j];
    __shared__ float es[32][16];
    __shared__ float dg[32];
    for (int c = 0; c < 4; ++c) {
        int rbase = r0 + c * 32;
        __syncthreads();
        if (threadIdx.x < 128) {
            int rr = threadIdx.x >> 2, kk = (threadIdx.x & 3) << 2;
            int r = rbase + rr;
            float4 e = make_float4(0.f, 0.f, 0.f, 0.f);
            if (r < NN) e = *(const float4*)(esum + (size_t)r * 16 + kk);
            *(float4*)&es[rr][kk] = e;
        } else if (threadIdx.x < 160) {
            int rr = threadIdx.x - 128;
            int r = rbase + rr;
            dg[rr] = (r < NN) ? degf[r] : 0.f;
        }
        __syncthreads();
        for (int rr = 0; rr < 32; ++rr) {
            int r = rbase + rr;
            if (r >= NN) break;
            float acc = fmaf(bj, dg[rr], bc);
#pragma unroll
            for (int k = 0; k < 16; ++k) acc = fmaf(es[rr][k], wj[k], acc);
            bias_row[((size_t)t * NN + r) * 192 + j] = acc;
        }
    }
}

// BT[t][n][k]: n<256, k<192.
//  n in [0,128):  k<128 -> WcT[t][n][k];      k>=128 -> W_hh[t][n][k-128]
//  n in [128,192):k<128 -> WcT[t][n][k];      k>=128 -> 0
//  n in [192,256):k<128 -> 0;                 k>=128 -> W_hh[t][n-64][k-128]
__global__ void wbig_kernel(const float* __restrict__ WcT,
                            const float* __restrict__ W_hh,
                            float* __restrict__ BT) {
    int idx = blockIdx.x * 256 + threadIdx.x;
    if (idx >= 2 * 256 * 192) return;
    int t = idx / (256 * 192);
    int rem = idx % (256 * 192);
    int n = rem / 192, k = rem % 192;
    float v = 0.f;
    if (n < 128) {
        v = (k < 128) ? WcT[((size_t)t * 192 + n) * 144 + k]
                      : W_hh[(size_t)t * 192 * 64 + n * 64 + (k - 128)];
    } else if (n < 192) {
        if (k < 128) v = WcT[((size_t)t * 192 + n) * 144 + k];
    } else {
        if (k >= 128) v = W_hh[(size_t)t * 192 * 64 + (n - 64) * 64 + (k - 128)];
    }
    BT[idx] = v;
}

// ---------------- per-round ----------------
// A[v][192] = [ deg*hv[v] | S[v]=sum_fp16 hf[src] | hv[v] ]
__global__ __launch_bounds__(256) void gather_kernel(
        const float* __restrict__ hv, const unsigned short* __restrict__ hf,
        const int* __restrict__ row_ptr, const int2* __restrict__ adj,
        float* __restrict__ A) {
    int wid = threadIdx.x >> 6, lane = threadIdx.x & 63;
    int v = blockIdx.x * 4 + wid;
    if (v >= NN) return;
    int rp0 = row_ptr[v], rp1 = row_ptr[v + 1];
    int q = lane >> 4;
    int fo = (lane & 15) << 2;           // element offset: 4 halfs (8B) per lane
    float4 acc[8];
#pragma unroll
    for (int u = 0; u < 8; ++u) acc[u] = make_float4(0.f, 0.f, 0.f, 0.f);
    int i = rp0 + q;
    for (; i + 28 < rp1; i += 32) {
        int s[8];
#pragma unroll
        for (int u = 0; u < 8; ++u) s[u] = adj[i + 4 * u].x;
#pragma unroll
        for (int u = 0; u < 8; ++u) {
            ushort4 x = *(const ushort4*)(hf + (size_t)s[u] * 64 + fo);
            acc[u].x += h2f(x.x); acc[u].y += h2f(x.y);
            acc[u].z += h2f(x.z); acc[u].w += h2f(x.w);
        }
    }
    for (; i + 4 < rp1; i += 8) {
        int s0 = adj[i].x, s1 = adj[i + 4].x;
        ushort4 x0 = *(const ushort4*)(hf + (size_t)s0 * 64 + fo);
        ushort4 x1 = *(const ushort4*)(hf + (size_t)s1 * 64 + fo);
        acc[0].x += h2f(x0.x); acc[0].y += h2f(x0.y);
        acc[0].z += h2f(x0.z); acc[0].w += h2f(x0.w);
        acc[1].x += h2f(x1.x); acc[1].y += h2f(x1.y);
        acc[1].z += h2f(x1.z); acc[1].w += h2f(x1.w);
    }
    for (; i < rp1; i += 4) {
        int s = adj[i].x;
        ushort4 x = *(const ushort4*)(hf + (size_t)s * 64 + fo);
        acc[0].x += h2f(x.x); acc[0].y += h2f(x.y);
        acc[0].z += h2f(x.z); acc[0].w += h2f(x.w);
    }
#pragma unroll
    for (int u = 1; u < 8; ++u) {
        acc[0].x += acc[u].x; acc[0].y += acc[u].y;
        acc[0].z += acc[u].z; acc[0].w += acc[u].w;
    }
#pragma unroll
    for (int m = 16; m < 64; m <<= 1) {
        acc[0].x += __shfl_xor(acc[0].x, m);
        acc[0].y += __shfl_xor(acc[0].y, m);
        acc[0].z += __shfl_xor(acc[0].z, m);
        acc[0].w += __shfl_xor(acc[0].w, m);
    }
    if (lane < 16) {
        float dg = (float)(rp1 - rp0);
        float4 hvv = *(const float4*)(hv + (size_t)v * 64 + fo);
        *(float4*)(A + (size_t)v * 192 + fo) =
            make_float4(dg * hvv.x, dg * hvv.y, dg * hvv.z, dg * hvv.w);
        *(float4*)(A + (size_t)v * 192 + 64 + fo) = acc[0];
        *(float4*)(A + (size_t)v * 192 + 128 + fo) = hvv;
    }
}

// C[M,256] = A[M,192] @ BT[256,192]^T with per-column-block K range:
//  cols [0,128): K=[0,192); cols [128,192): K=[0,128); cols [192,256): K=[128,192)
__global__ __launch_bounds__(256) void gemm_fused(
    const float* __restrict__ A, const float* __restrict__ BT,
    float* __restrict__ C, int M) {
    const int LDA = 192, LDB = 192, NOUT = 256, BK = 32;
    __shared__ float As[32][132];
    __shared__ float Bs[32][68];
    int tid = threadIdx.x;
    int ty = tid >> 4, tx = tid & 15;
    int row0 = blockIdx.x * 128;
    int by = blockIdx.y;
    int col0 = by * 64;
    int k_lo = (by == 3) ? 128 : 0;
    int k_hi = (by == 2) ? 128 : 192;
    float acc[8][4];
#pragma unroll
    for (int i = 0; i < 8; ++i)
#pragma unroll
        for (int j = 0; j < 4; ++j) acc[i][j] = 0.f;

    int lr = tid >> 3;
    int lk = (tid & 7) << 2;

    for (int k0 = k_lo; k0 < k_hi; k0 += BK) {
#pragma unroll
        for (int p = 0; p < 4; ++p) {
            int r = lr + p * 32;
            float4 v = make_float4(0.f, 0.f, 0.f, 0.f);
            int gr = row0 + r;
            if (gr < M) v = *(const float4*)(A + (size_t)gr * LDA + k0 + lk);
            As[lk + 0][r] = v.x; As[lk + 1][r] = v.y;
            As[lk + 2][r] = v.z; As[lk + 3][r] = v.w;
        }
#pragma unroll
        for (int p = 0; p < 2; ++p) {
            int n = lr + p * 32;
            float4 v = *(const float4*)(BT + (size_t)(col0 + n) * LDB + k0 + lk);
            Bs[lk + 0][n] = v.x; Bs[lk + 1][n] = v.y;
            Bs[lk + 2][n] = v.z; Bs[lk + 3][n] = v.w;
        }
        __syncthreads();
#pragma unroll
        for (int kk = 0; kk < BK; ++kk) {
            float4 a0 = *(const float4*)&As[kk][ty * 8];
            float4 a1 = *(const float4*)&As[kk][ty * 8 + 4];
            float4 b0 = *(const float4*)&Bs[kk][tx * 4];
            float av[8] = {a0.x, a0.y, a0.z, a0.w, a1.x, a1.y, a1.z, a1.w};
            float bv[4] = {b0.x, b0.y, b0.z, b0.w};
#pragma unroll
            for (int i = 0; i < 8; ++i)
#pragma unroll
                for (int j = 0; j < 4; ++j)
                    acc[i][j] = fmaf(av[i], bv[j], acc[i][j]);
        }
        __syncthreads();
    }

    int c = col0 + tx * 4;
#pragma unroll
    for (int i = 0; i < 8; ++i) {
        int r = row0 + ty * 8 + i;
        if (r >= M) continue;
        float4 o = make_float4(acc[i][0], acc[i][1], acc[i][2], acc[i][3]);
        *(float4*)(C + (size_t)r * NOUT + c) = o;
    }
}

// gates: r=sig(c_r+br_r+bhh_r), z=sig(c_z+br_z+bhh_z), n=tanh(c_in+br_n + r*(c_hn+bhh_n))
__global__ void gate_kernel(const float* __restrict__ C, const float* __restrict__ bias_row,
                            const float* __restrict__ b_hh, const float* __restrict__ hin,
                            float* __restrict__ out, __half* __restrict__ hfout) {
    int idx = blockIdx.x * blockDim.x + threadIdx.x;
    if (idx >= NN * 64) return;
    int v = idx >> 6, j = idx & 63;
    const float* c = C + (size_t)v * 256;
    const float* br = bias_row + (size_t)v * 192;
    float rr = c[j] + br[j] + b_hh[j];
    float zz = c[64 + j] + br[64 + j] + b_hh[64 + j];
    float in_ = c[128 + j] + br[128 + j];
    float hn = c[192 + j] + b_hh[128 + j];
    float r = 1.f / (1.f + __expf(-rr));
    float z = 1.f / (1.f + __expf(-zz));
    float n = tanhf(in_ + r * hn);
    float h = hin[idx];
    float val = (1.f - z) * n + z * h;
    out[idx] = val;
    if (hfout) hfout[idx] = __float2half(val);
}

extern "C" void kernel_launch(void* const* d_in, const int* in_sizes, int n_in,
                              void* d_out, int out_size, void* d_ws, size_t ws_size,
                              hipStream_t stream) {
    const float* hv0   = (const float*)d_in[0];
    const float* ef    = (const float*)d_in[1];
    const int*   src   = (const int*)d_in[2];
    const int*   dst   = (const int*)d_in[3];
    const float* W_msg = (const float*)d_in[4];
    const float* b_msg = (const float*)d_in[5];
    const float* W_ih  = (const float*)d_in[6];
    const float* W_hh  = (const float*)d_in[7];
    const float* b_ih  = (const float*)d_in[8];
    const float* b_hh  = (const float*)d_in[9];
    float* out = (float*)d_out;

    char* ws = (char*)d_ws;
    size_t off = 0;
    auto alloc = [&](size_t bytes) -> char* {
        char* p = ws + off;
        off = (off + bytes + 255) & ~(size_t)255;
        return p;
    };
    int*   cnt4     = (int*)alloc((size_t)NC * NN * 4);
    int*   row_ptr  = (int*)alloc((NN + 1) * 4);
    int*   cursor4  = (int*)alloc((size_t)NC * NN * 4);
    int2*  adj      = (int2*)alloc((size_t)NE * 8);
    float* esum     = (float*)alloc((size_t)NN * 16 * 4);
    float* degf     = (float*)alloc(NN * 4);
    float* A        = (float*)alloc((size_t)NN * 192 * 4);
    float* Cbuf     = (float*)alloc((size_t)NN * 256 * 4);
    float* hv1      = (float*)alloc((size_t)NN * 64 * 4);
    float* WcT      = (float*)alloc((size_t)2 * 192 * 144 * 4);
    float* bvec     = (float*)alloc(2 * 192 * 4);
    float* BT       = (float*)alloc((size_t)2 * 256 * 192 * 4);
    int*   lp       = (int*)alloc(NN * 4);
    int*   bsum     = (int*)alloc(NB_SCAN * 4);
    int*   boff     = (int*)alloc(NB_SCAN * 4);
    __half* hf0     = (__half*)alloc((size_t)NN * 64 * 2);
    __half* hf1     = (__half*)alloc((size_t)NN * 64 * 2);
    float* bias_row = (float*)alloc((size_t)2 * NN * 192 * 4);

    zero_kernel<<<(NC * NN + 1023) / 1024, 1024, 0, stream>>>(cnt4, NC * NN);
    tohf_kernel<<<(NN * 64 + 255) / 256, 256, 0, stream>>>(hv0, hf0, NN * 64);
    hist_kernel<<<(NE + 255) / 256, 256, 0, stream>>>(dst, cnt4);
    scan1_kernel<<<NB_SCAN, 256, 0, stream>>>(cnt4, lp, bsum);
    scan2_kernel<<<1, 128, 0, stream>>>(bsum, boff);
    scan3_kernel<<<NB_SCAN, 256, 0, stream>>>(cnt4, lp, boff, row_ptr, cursor4);
    place_kernel<<<(NE + 255) / 256, 256, 0, stream>>>(src, dst, cursor4, adj);
    esum_csr_kernel<<<(NN + 3) / 4, 256, 0, stream>>>(ef, row_ptr, adj, esum, degf);
    fold_kernel<<<18, 192, 0, stream>>>(W_msg, b_msg, W_ih, WcT, bvec);
    wbig_kernel<<<(2 * 256 * 192 + 255) / 256, 256, 0, stream>>>(WcT, W_hh, BT);
    dim3 gb((NN + 127) / 128, 2);
    biasrow_kernel<<<gb, 192, 0, stream>>>(WcT, bvec, b_ih, esum, degf, bias_row);

    for (int t = 0; t < 2; ++t) {
        const float* hin = (t == 0) ? hv0 : hv1;
        const __half* hfin = (t == 0) ? hf0 : hf1;
        float* hout = (t == 1) ? out : hv1;
        gather_kernel<<<(NN + 3) / 4, 256, 0, stream>>>(
            hin, (const unsigned short*)hfin, row_ptr, adj, A);
        dim3 g1((NN + 127) / 128, 4);
        gemm_fused<<<g1, 256, 0, stream>>>(A, BT + (size_t)t * 256 * 192, Cbuf, NN);
        gate_kernel<<<(NN * 64 + 255) / 256, 256, 0, stream>>>(
            Cbuf, bias_row + (size_t)t * NN * 192, b_hh + t * 192, hin, hout,
            (t == 0) ? hf1 : (__half*)nullptr);
    }
}